// Round 8
// baseline (373.326 us; speedup 1.0000x reference)
//
#include <hip/hip_runtime.h>

namespace {

constexpr float kAlpha = 0.025f;
constexpr float kC1 = 1.0e-4f;  // (0.01*1)^2
constexpr float kC2 = 9.0e-4f;  // (0.03*1)^2

constexpr int MPS = 72;  // mp row stride (shorts): 144 B, b128-aligned rows
constexpr int HTS = 68;  // hbT col stride (shorts): 136 B, b64-aligned

typedef __attribute__((ext_vector_type(8))) short short8;
typedef __attribute__((ext_vector_type(4))) float f32x4;

// LDS: mp 18,432 B + hbT 21,760 B + red 16 B ~= 40.2 KB -> 3 blocks/CU
struct __align__(16) Smem {
  short mp[2][64 * MPS];   // bf16 pixel maps: x, y (used only for sigma-0 A-load)
  short hbT[5][32 * HTS];  // bf16 H-conv results, transposed [out_col][row]
  float red[4];
};

union Frag {
  int i[4];
  int4 i4;
  short8 s8;
};

__device__ __forceinline__ unsigned f2bf(float f) {  // RNE fp32 -> bf16 bits
  unsigned u = __float_as_uint(f);
  return (u + 0x7FFFu + ((u >> 16) & 1u)) >> 16;
}
__device__ __forceinline__ unsigned pack2(float a, float b) {
  return f2bf(a) | (f2bf(b) << 16);
}
__device__ __forceinline__ float bfl(unsigned u) {  // low bf16 -> f32
  return __uint_as_float(u << 16);
}
__device__ __forceinline__ float bfh(unsigned u) {  // high bf16 -> f32
  return __uint_as_float(u & 0xFFFF0000u);
}

// One sigma, full 33-tap band as banded matmul:
//  WH[k][n] = g[k-n], k-n in [0,32]; H(64x32) = In(64x64) x WH
//  WV = WH^T (same lane fragments);  Out(32x32) = WV(32x64) x H
// tb: per-lane bf16 tap bits (lane j<33 holds g[j], else 0).
template <bool LAST>
__device__ __forceinline__ void do_sigma(Smem& sm, unsigned tb, int tid,
                                         const Frag a[4][2], f32x4& Pcs,
                                         f32x4& lumP, f32x4& l1v, float corr) {
  const int lane = tid & 63;
  const int w = tid >> 6;  // wave id
  const int quad = lane >> 4;
  const int l16 = lane & 15;

  // ---- W fragments via lane shuffles: wf[nt][kt] element (p,h) =
  //      g[idx], idx = quad*8+2p+h - l16 + 32*kt - 16*nt; lanes>=33 hold 0,
  //      index wrap (&63) maps all out-of-band idx onto zero lanes. ----
  short8 wf[2][2];
  const int base = quad * 8 - l16;
#pragma unroll
  for (int nt = 0; nt < 2; ++nt)
#pragma unroll
    for (int kt = 0; kt < 2; ++kt) {
      Frag u;
      const int b0 = base + 32 * kt - 16 * nt;
#pragma unroll
      for (int p = 0; p < 4; ++p) {
        unsigned lo = (unsigned)__shfl((int)tb, (b0 + 2 * p) & 63, 64);
        unsigned hi = (unsigned)__shfl((int)tb, (b0 + 2 * p + 1) & 63, 64);
        u.i[p] = (int)(lo | (hi << 16));
      }
      wf[nt][kt] = u.s8;
    }

  __syncthreads();  // B1: prev sigma's V reads of hbT complete

  // ---- H GEMM: wave w owns mtile w (rows w*16..+16); A-frags cached ----
  {
    Frag d0, d1;
    if (LAST) {  // |x-y| fragments from cached x/y fragments
#pragma unroll
      for (int i = 0; i < 4; ++i) {
        unsigned ux0 = (unsigned)a[0][0].i[i], uy0 = (unsigned)a[1][0].i[i];
        unsigned ux1 = (unsigned)a[0][1].i[i], uy1 = (unsigned)a[1][1].i[i];
        d0.i[i] = (int)pack2(fabsf(bfl(ux0) - bfl(uy0)),
                             fabsf(bfh(ux0) - bfh(uy0)));
        d1.i[i] = (int)pack2(fabsf(bfl(ux1) - bfl(uy1)),
                             fabsf(bfh(ux1) - bfh(uy1)));
      }
    }
#pragma unroll
    for (int m = 0; m < (LAST ? 5 : 4); ++m) {
      short8 f0 = (LAST && m == 4) ? d0.s8 : a[m][0].s8;
      short8 f1 = (LAST && m == 4) ? d1.s8 : a[m][1].s8;
#pragma unroll
      for (int nt = 0; nt < 2; ++nt) {
        f32x4 acc = {0.f, 0.f, 0.f, 0.f};
        acc = __builtin_amdgcn_mfma_f32_16x16x32_bf16(f0, wf[nt][0], acc, 0, 0,
                                                      0);
        acc = __builtin_amdgcn_mfma_f32_16x16x32_bf16(f1, wf[nt][1], acc, 0, 0,
                                                      0);
        // C/D: col=l16, row=quad*4+reg -> store transposed as bf16
        *(int2*)(&sm.hbT[m][(nt * 16 + l16) * HTS + w * 16 + quad * 4]) =
            make_int2((int)pack2(acc[0], acc[1]), (int)pack2(acc[2], acc[3]));
      }
    }
  }
  __syncthreads();  // B2: hbT ready

  // ---- V GEMM: wave quadrant (mtv = w>>1, ntv = w&1); A-frags = wf[mtv] ----
  const int mtv = w >> 1, ntv = w & 1;
  f32x4 va[LAST ? 5 : 4];
#pragma unroll
  for (int m = 0; m < (LAST ? 5 : 4); ++m) {
    const short* bp = sm.hbT[m] + (ntv * 16 + l16) * HTS + quad * 8;
    Frag b0, b1;
    *(int2*)&b0.i[0] = *(const int2*)(bp);
    *(int2*)&b0.i[2] = *(const int2*)(bp + 4);
    *(int2*)&b1.i[0] = *(const int2*)(bp + 32);
    *(int2*)&b1.i[2] = *(const int2*)(bp + 36);
    f32x4 acc = {0.f, 0.f, 0.f, 0.f};
    acc = __builtin_amdgcn_mfma_f32_16x16x32_bf16(wf[mtv][0], b0.s8, acc, 0, 0,
                                                  0);
    acc = __builtin_amdgcn_mfma_f32_16x16x32_bf16(wf[mtv][1], b1.s8, acc, 0, 0,
                                                  0);
    va[m] = acc;
  }

  // ---- combine in registers: pixel (mtv*16+quad*4+r, ntv*16+l16) ----
#pragma unroll
  for (int r = 0; r < 4; ++r) {
    float mux = va[0][r], muy = va[1][r], m2 = va[2][r], mxy = va[3][r];
    float mux2 = mux * mux, muy2 = muy * muy, muxy = mux * muy;
    float cs = (2.f * (mxy - muxy) + kC2) / ((m2 - mux2 - muy2) + kC2);
    Pcs[r] *= cs;
    if (LAST) {
      lumP[r] = ((2.f * muxy + kC1) / (mux2 + muy2 + kC1)) * Pcs[r];
      l1v[r] = va[4][r] * corr;
    }
  }
}

__global__ __launch_bounds__(256, 3) void msssim_l1_kernel(
    const float* __restrict__ x, const float* __restrict__ y,
    const float* __restrict__ gm, float* __restrict__ out) {
  __shared__ Smem sm;
  const int tid = threadIdx.x;
  const int lane = tid & 63;
  const int w = tid >> 6;
  const int quad = lane >> 4;
  const int l16 = lane & 15;

  // per-lane raw taps: lane j<33 holds mask-row value m[16][j] per sigma
  float traw[5];
#pragma unroll
  for (int s = 0; s < 5; ++s)
    traw[s] = (lane < 33) ? gm[s * 1089 + 16 * 33 + lane] : 0.f;

  // 64x64 halo patch, zero-padded; build bf16 x/y maps in LDS
  const float* xb = x + blockIdx.z * (512 * 512);
  const float* yb = y + blockIdx.z * (512 * 512);
  const int rb = blockIdx.y * 32 - 16;
  const int cb = blockIdx.x * 32 - 16;
  for (int f = tid; f < 1024; f += 256) {
    int pr = f >> 4;
    int pc = (f & 15) << 2;
    int gr = rb + pr, gc = cb + pc;
    float4 vx = make_float4(0.f, 0.f, 0.f, 0.f);
    float4 vy = vx;
    if (gr >= 0 && gr < 512 && gc >= 0 && gc < 512) {
      vx = *(const float4*)(xb + gr * 512 + gc);
      vy = *(const float4*)(yb + gr * 512 + gc);
    }
    const int base = pr * MPS + pc;  // shorts; byte offset 8-aligned
    *(int2*)(&sm.mp[0][base]) =
        make_int2((int)pack2(vx.x, vx.y), (int)pack2(vx.z, vx.w));
    *(int2*)(&sm.mp[1][base]) =
        make_int2((int)pack2(vy.x, vy.y), (int)pack2(vy.z, vy.w));
  }
  __syncthreads();  // patch ready

  // ---- cache A-fragments for this wave's row tile (rows w*16..w*16+15) ----
  Frag a[4][2];  // maps: 0=x, 1=y, 2=x^2+y^2, 3=xy; two K-halves
  {
    const short* apx = sm.mp[0] + (w * 16 + l16) * MPS + quad * 8;
    const short* apy = sm.mp[1] + (w * 16 + l16) * MPS + quad * 8;
    a[0][0].i4 = *(const int4*)(apx);
    a[0][1].i4 = *(const int4*)(apx + 32);
    a[1][0].i4 = *(const int4*)(apy);
    a[1][1].i4 = *(const int4*)(apy + 32);
#pragma unroll
    for (int half = 0; half < 2; ++half) {
#pragma unroll
      for (int i = 0; i < 4; ++i) {
        unsigned ux = (unsigned)a[0][half].i[i], uy = (unsigned)a[1][half].i[i];
        float xl = bfl(ux), xh = bfh(ux), yl = bfl(uy), yh = bfh(uy);
        a[2][half].i[i] =
            (int)pack2(fmaf(xl, xl, yl * yl), fmaf(xh, xh, yh * yh));
        a[3][half].i[i] = (int)pack2(xl * yl, xh * yh);
      }
    }
  }

  f32x4 Pcs = {1.f, 1.f, 1.f, 1.f};
  f32x4 lumP = {0.f, 0.f, 0.f, 0.f};
  f32x4 l1v = {0.f, 0.f, 0.f, 0.f};

  // per-sigma tap bits + sigma-4 bf16 compensation factor
  float corr;
  {
    float se = traw[4], st = bfl(f2bf(traw[4] * rsqrtf(__shfl(traw[4], 16, 64))));
    // normalize se the same way st is: se = sum(g), st = sum(bf16(g))
    float rsc4 = rsqrtf(__shfl(traw[4], 16, 64));
    se = traw[4] * rsc4;
#pragma unroll
    for (int off = 32; off > 0; off >>= 1) {
      se += __shfl_xor(se, off, 64);
      st += __shfl_xor(st, off, 64);
    }
    float r1 = se / st;
    corr = r1 * r1;
  }

#pragma unroll
  for (int s = 0; s < 5; ++s) {
    float rsc = rsqrtf(__shfl(traw[s], 16, 64));
    unsigned tb = f2bf(traw[s] * rsc);  // lane>=33: 0
    if (s < 4)
      do_sigma<false>(sm, tb, tid, a, Pcs, lumP, l1v, corr);
    else
      do_sigma<true>(sm, tb, tid, a, Pcs, lumP, l1v, corr);
  }

  // loss_mix = alpha*(1 - lum*PIcs) + (1-alpha)*gaussian_l1 ; out = 20*mean
  float lsum = 0.f;
#pragma unroll
  for (int r = 0; r < 4; ++r)
    lsum += kAlpha * (1.f - lumP[r]) + (1.f - kAlpha) * l1v[r];
#pragma unroll
  for (int off = 32; off > 0; off >>= 1) lsum += __shfl_down(lsum, off, 64);
  if ((tid & 63) == 0) sm.red[tid >> 6] = lsum;
  __syncthreads();
  if (tid == 0) {
    float t = sm.red[0] + sm.red[1] + sm.red[2] + sm.red[3];
    atomicAdd(out, t * (20.f / (16.f * 512.f * 512.f)));
  }
}

}  // namespace

extern "C" void kernel_launch(void* const* d_in, const int* in_sizes, int n_in,
                              void* d_out, int out_size, void* d_ws,
                              size_t ws_size, hipStream_t stream) {
  (void)in_sizes;
  (void)n_in;
  (void)d_ws;
  (void)ws_size;
  (void)out_size;
  const float* x = (const float*)d_in[0];
  const float* y = (const float*)d_in[1];
  const float* gm = (const float*)d_in[2];
  float* out = (float*)d_out;
  hipMemsetAsync(out, 0, sizeof(float), stream);
  dim3 grid(16, 16, 16);
  msssim_l1_kernel<<<grid, dim3(256), 0, stream>>>(x, y, gm, out);
}

// Round 9
// 192.630 us; speedup vs baseline: 1.9380x; 1.9380x over previous
//
#include <hip/hip_runtime.h>

namespace {

constexpr float kAlpha = 0.025f;
constexpr float kC1 = 1.0e-4f;  // (0.01*1)^2
constexpr float kC2 = 9.0e-4f;  // (0.03*1)^2

constexpr int MPS = 68;  // mp row stride (shorts): 136 B, b64-aligned rows
constexpr int HTS = 68;  // hbT col stride (shorts): 136 B, b64-aligned

typedef __attribute__((ext_vector_type(8))) short short8;
typedef __attribute__((ext_vector_type(4))) float f32x4;

// LDS: mp 17,408 B + hbT 52,224 B + red 16 B ~= 68 KB -> 2 blocks/CU
// group1 planes: sigma s in {0,1,2}, map m -> plane s*4+m  (12 planes)
// group2 planes: sigma 3 map m -> plane m; sigma 4 map m -> plane 4+m (9)
struct __align__(16) Smem {
  short mp[2][64 * MPS];    // bf16 pixel maps: x, y
  short hbT[12][32 * HTS];  // bf16 H results, transposed [out_col n][row k]
  float red[4];
};

union Frag {
  int i[4];
  short8 s8;
};

__device__ __forceinline__ unsigned f2bf(float f) {  // RNE fp32 -> bf16 bits
  unsigned u = __float_as_uint(f);
  return (u + 0x7FFFu + ((u >> 16) & 1u)) >> 16;
}
__device__ __forceinline__ unsigned pack2(float a, float b) {
  return f2bf(a) | (f2bf(b) << 16);
}
__device__ __forceinline__ float bfl(unsigned u) {
  return __uint_as_float(u << 16);
}
__device__ __forceinline__ float bfh(unsigned u) {
  return __uint_as_float(u & 0xFFFF0000u);
}

// W fragment via lane shuffles: element (p,h) = g[k - n],
// k = kt*32 + quad*8 + 2p+h, n = nt*16 + l16; lanes >= 33 hold 0 and the
// &63 wrap maps every out-of-band index onto a zero lane.
// Works for both B-operand (H pass, nt = ntile) and A-operand (V pass,
// nt = mtile) because A(m,k) and B(k,n) lane layouts are symmetric.
__device__ __forceinline__ short8 wbuild(unsigned tb, int lane, int nt,
                                         int kt) {
  const int b0 = (lane >> 4) * 8 - (lane & 15) + 32 * kt - 16 * nt;
  Frag u;
#pragma unroll
  for (int p = 0; p < 4; ++p) {
    unsigned lo = (unsigned)__shfl((int)tb, (b0 + 2 * p) & 63, 64);
    unsigned hi = (unsigned)__shfl((int)tb, (b0 + 2 * p + 1) & 63, 64);
    u.i[p] = (int)(lo | (hi << 16));
  }
  return u.s8;
}

__device__ __forceinline__ void load_xy(const Smem& sm, int row, int quad,
                                        Frag fx[2], Frag fy[2]) {
  const short* px = &sm.mp[0][row * MPS + quad * 8];
  const short* py = &sm.mp[1][row * MPS + quad * 8];
  *(int2*)&fx[0].i[0] = *(const int2*)(px);
  *(int2*)&fx[0].i[2] = *(const int2*)(px + 4);
  *(int2*)&fx[1].i[0] = *(const int2*)(px + 32);
  *(int2*)&fx[1].i[2] = *(const int2*)(px + 36);
  *(int2*)&fy[0].i[0] = *(const int2*)(py);
  *(int2*)&fy[0].i[2] = *(const int2*)(py + 4);
  *(int2*)&fy[1].i[0] = *(const int2*)(py + 32);
  *(int2*)&fy[1].i[2] = *(const int2*)(py + 36);
}

__global__ __launch_bounds__(256, 2) void msssim_l1_kernel(
    const float* __restrict__ x, const float* __restrict__ y,
    const float* __restrict__ gm, float* __restrict__ out) {
  __shared__ Smem sm;
  const int tid = threadIdx.x;
  const int lane = tid & 63;
  const int w = tid >> 6;
  const int quad = lane >> 4;
  const int l16 = lane & 15;

  // per-lane taps (lane j<33 holds m[16][j]); per-sigma bf16 tap bits
  float traw[5];
#pragma unroll
  for (int s = 0; s < 5; ++s)
    traw[s] = (lane < 33) ? gm[s * 1089 + 16 * 33 + lane] : 0.f;
  unsigned tbs[5];
#pragma unroll
  for (int s = 0; s < 5; ++s)
    tbs[s] = f2bf(traw[s] * rsqrtf(__shfl(traw[s], 16, 64)));
  float corr;  // fp32/bf16 tap-sum compensation for the l1 conv (sigma 4)
  {
    float g = traw[4] * rsqrtf(__shfl(traw[4], 16, 64));
    float se = g, st = bfl(f2bf(g));
#pragma unroll
    for (int off = 32; off > 0; off >>= 1) {
      se += __shfl_xor(se, off, 64);
      st += __shfl_xor(st, off, 64);
    }
    float r1 = se / st;
    corr = r1 * r1;
  }

  // 64x64 halo patch, zero-padded; bf16 x/y maps in LDS
  const float* xb = x + blockIdx.z * (512 * 512);
  const float* yb = y + blockIdx.z * (512 * 512);
  const int rb = blockIdx.y * 32 - 16;
  const int cb = blockIdx.x * 32 - 16;
  for (int f = tid; f < 1024; f += 256) {
    int pr = f >> 4;
    int pc = (f & 15) << 2;
    int gr = rb + pr, gc = cb + pc;
    float4 vx = make_float4(0.f, 0.f, 0.f, 0.f);
    float4 vy = vx;
    if (gr >= 0 && gr < 512 && gc >= 0 && gc < 512) {
      vx = *(const float4*)(xb + gr * 512 + gc);
      vy = *(const float4*)(yb + gr * 512 + gc);
    }
    const int base = pr * MPS + pc;
    *(int2*)(&sm.mp[0][base]) =
        make_int2((int)pack2(vx.x, vx.y), (int)pack2(vx.z, vx.w));
    *(int2*)(&sm.mp[1][base]) =
        make_int2((int)pack2(vy.x, vy.y), (int)pack2(vy.z, vy.w));
  }
  __syncthreads();  // B1: patch ready

  // persistent A-fragments for THIS wave's map (m = w), all 4 row tiles
  Frag A[4][2];
#pragma unroll
  for (int mt = 0; mt < 4; ++mt) {
    Frag fx[2], fy[2];
    load_xy(sm, mt * 16 + l16, quad, fx, fy);
    if (w == 0) {
      A[mt][0] = fx[0];
      A[mt][1] = fx[1];
    } else if (w == 1) {
      A[mt][0] = fy[0];
      A[mt][1] = fy[1];
    } else {
#pragma unroll
      for (int h = 0; h < 2; ++h)
#pragma unroll
        for (int i = 0; i < 4; ++i) {
          unsigned ux = (unsigned)fx[h].i[i], uy = (unsigned)fy[h].i[i];
          float xl = bfl(ux), xh = bfh(ux), yl = bfl(uy), yh = bfh(uy);
          A[mt][h].i[i] = (w == 2) ? (int)pack2(fmaf(xl, xl, yl * yl),
                                               fmaf(xh, xh, yh * yh))
                                   : (int)pack2(xl * yl, xh * yh);
        }
    }
  }

  const int mtv = w >> 1, ntv = w & 1;
  f32x4 Pcs = {1.f, 1.f, 1.f, 1.f};
  f32x4 lumP = {0.f, 0.f, 0.f, 0.f};
  f32x4 l1v = {0.f, 0.f, 0.f, 0.f};

  // ================= group 1: sigmas 0..2 =================
#pragma unroll
  for (int s = 0; s < 3; ++s) {  // H: wave w = map w, plane s*4+w
    short8 wf[2][2];
#pragma unroll
    for (int nt = 0; nt < 2; ++nt)
#pragma unroll
      for (int kt = 0; kt < 2; ++kt) wf[nt][kt] = wbuild(tbs[s], lane, nt, kt);
#pragma unroll
    for (int mt = 0; mt < 4; ++mt)
#pragma unroll
      for (int nt = 0; nt < 2; ++nt) {
        f32x4 acc = {0.f, 0.f, 0.f, 0.f};
        acc = __builtin_amdgcn_mfma_f32_16x16x32_bf16(A[mt][0].s8, wf[nt][0],
                                                      acc, 0, 0, 0);
        acc = __builtin_amdgcn_mfma_f32_16x16x32_bf16(A[mt][1].s8, wf[nt][1],
                                                      acc, 0, 0, 0);
        *(int2*)(&sm.hbT[s * 4 + w][(nt * 16 + l16) * HTS + mt * 16 +
                                    quad * 4]) =
            make_int2((int)pack2(acc[0], acc[1]), (int)pack2(acc[2], acc[3]));
      }
  }
  __syncthreads();  // B2: group-1 hbT ready

#pragma unroll
  for (int s = 0; s < 3; ++s) {  // V + combine: wave = output quadrant
    short8 wa0 = wbuild(tbs[s], lane, mtv, 0);
    short8 wa1 = wbuild(tbs[s], lane, mtv, 1);
    f32x4 va[4];
#pragma unroll
    for (int m = 0; m < 4; ++m) {
      const short* bp = &sm.hbT[s * 4 + m][(ntv * 16 + l16) * HTS + quad * 8];
      Frag b0, b1;
      *(int2*)&b0.i[0] = *(const int2*)(bp);
      *(int2*)&b0.i[2] = *(const int2*)(bp + 4);
      *(int2*)&b1.i[0] = *(const int2*)(bp + 32);
      *(int2*)&b1.i[2] = *(const int2*)(bp + 36);
      f32x4 acc = {0.f, 0.f, 0.f, 0.f};
      acc = __builtin_amdgcn_mfma_f32_16x16x32_bf16(wa0, b0.s8, acc, 0, 0, 0);
      acc = __builtin_amdgcn_mfma_f32_16x16x32_bf16(wa1, b1.s8, acc, 0, 0, 0);
      va[m] = acc;
    }
#pragma unroll
    for (int r = 0; r < 4; ++r) {
      float mux = va[0][r], muy = va[1][r], m2 = va[2][r], mxy = va[3][r];
      float cs = (2.f * (mxy - mux * muy) + kC2) /
                 ((m2 - mux * mux - muy * muy) + kC2);
      Pcs[r] *= cs;
    }
  }
  __syncthreads();  // B3: group-1 V reads done, hbT reusable

  // ================= group 2: sigmas 3,4 =================
#pragma unroll
  for (int s = 3; s < 5; ++s) {
    const int pb = (s == 3) ? 0 : 4;
    short8 wf[2][2];
#pragma unroll
    for (int nt = 0; nt < 2; ++nt)
#pragma unroll
      for (int kt = 0; kt < 2; ++kt) wf[nt][kt] = wbuild(tbs[s], lane, nt, kt);
#pragma unroll
    for (int mt = 0; mt < 4; ++mt)
#pragma unroll
      for (int nt = 0; nt < 2; ++nt) {
        f32x4 acc = {0.f, 0.f, 0.f, 0.f};
        acc = __builtin_amdgcn_mfma_f32_16x16x32_bf16(A[mt][0].s8, wf[nt][0],
                                                      acc, 0, 0, 0);
        acc = __builtin_amdgcn_mfma_f32_16x16x32_bf16(A[mt][1].s8, wf[nt][1],
                                                      acc, 0, 0, 0);
        *(int2*)(&sm.hbT[pb + w][(nt * 16 + l16) * HTS + mt * 16 + quad * 4]) =
            make_int2((int)pack2(acc[0], acc[1]), (int)pack2(acc[2], acc[3]));
      }
  }
  if (w == 0) {  // extra plane: sigma-4 |x-y| -> plane 8
    short8 wf[2][2];
#pragma unroll
    for (int nt = 0; nt < 2; ++nt)
#pragma unroll
      for (int kt = 0; kt < 2; ++kt) wf[nt][kt] = wbuild(tbs[4], lane, nt, kt);
#pragma unroll
    for (int mt = 0; mt < 4; ++mt) {
      Frag fx[2], fy[2], d[2];
      load_xy(sm, mt * 16 + l16, quad, fx, fy);
#pragma unroll
      for (int h = 0; h < 2; ++h)
#pragma unroll
        for (int i = 0; i < 4; ++i) {
          unsigned ux = (unsigned)fx[h].i[i], uy = (unsigned)fy[h].i[i];
          d[h].i[i] = (int)pack2(fabsf(bfl(ux) - bfl(uy)),
                                 fabsf(bfh(ux) - bfh(uy)));
        }
#pragma unroll
      for (int nt = 0; nt < 2; ++nt) {
        f32x4 acc = {0.f, 0.f, 0.f, 0.f};
        acc = __builtin_amdgcn_mfma_f32_16x16x32_bf16(d[0].s8, wf[nt][0], acc,
                                                      0, 0, 0);
        acc = __builtin_amdgcn_mfma_f32_16x16x32_bf16(d[1].s8, wf[nt][1], acc,
                                                      0, 0, 0);
        *(int2*)(&sm.hbT[8][(nt * 16 + l16) * HTS + mt * 16 + quad * 4]) =
            make_int2((int)pack2(acc[0], acc[1]), (int)pack2(acc[2], acc[3]));
      }
    }
  }
  __syncthreads();  // B4: group-2 hbT ready

#pragma unroll
  for (int s = 3; s < 5; ++s) {
    const int pb = (s == 3) ? 0 : 4;
    const int nm = (s == 3) ? 4 : 5;
    short8 wa0 = wbuild(tbs[s], lane, mtv, 0);
    short8 wa1 = wbuild(tbs[s], lane, mtv, 1);
    f32x4 va[5];
#pragma unroll
    for (int m = 0; m < 5; ++m) {
      if (m >= nm) continue;
      const short* bp = &sm.hbT[pb + m][(ntv * 16 + l16) * HTS + quad * 8];
      Frag b0, b1;
      *(int2*)&b0.i[0] = *(const int2*)(bp);
      *(int2*)&b0.i[2] = *(const int2*)(bp + 4);
      *(int2*)&b1.i[0] = *(const int2*)(bp + 32);
      *(int2*)&b1.i[2] = *(const int2*)(bp + 36);
      f32x4 acc = {0.f, 0.f, 0.f, 0.f};
      acc = __builtin_amdgcn_mfma_f32_16x16x32_bf16(wa0, b0.s8, acc, 0, 0, 0);
      acc = __builtin_amdgcn_mfma_f32_16x16x32_bf16(wa1, b1.s8, acc, 0, 0, 0);
      va[m] = acc;
    }
#pragma unroll
    for (int r = 0; r < 4; ++r) {
      float mux = va[0][r], muy = va[1][r], m2 = va[2][r], mxy = va[3][r];
      float mux2 = mux * mux, muy2 = muy * muy, muxy = mux * muy;
      float cs = (2.f * (mxy - muxy) + kC2) / ((m2 - mux2 - muy2) + kC2);
      Pcs[r] *= cs;
      if (s == 4) {
        lumP[r] = ((2.f * muxy + kC1) / (mux2 + muy2 + kC1)) * Pcs[r];
        l1v[r] = va[4][r] * corr;
      }
    }
  }

  // loss_mix = alpha*(1 - lum*PIcs) + (1-alpha)*gaussian_l1 ; out = 20*mean
  float lsum = 0.f;
#pragma unroll
  for (int r = 0; r < 4; ++r)
    lsum += kAlpha * (1.f - lumP[r]) + (1.f - kAlpha) * l1v[r];
#pragma unroll
  for (int off = 32; off > 0; off >>= 1) lsum += __shfl_down(lsum, off, 64);
  if ((tid & 63) == 0) sm.red[tid >> 6] = lsum;
  __syncthreads();  // B5
  if (tid == 0) {
    float t = sm.red[0] + sm.red[1] + sm.red[2] + sm.red[3];
    atomicAdd(out, t * (20.f / (16.f * 512.f * 512.f)));
  }
}

}  // namespace

extern "C" void kernel_launch(void* const* d_in, const int* in_sizes, int n_in,
                              void* d_out, int out_size, void* d_ws,
                              size_t ws_size, hipStream_t stream) {
  (void)in_sizes;
  (void)n_in;
  (void)d_ws;
  (void)ws_size;
  (void)out_size;
  const float* x = (const float*)d_in[0];
  const float* y = (const float*)d_in[1];
  const float* gm = (const float*)d_in[2];
  float* out = (float*)d_out;
  hipMemsetAsync(out, 0, sizeof(float), stream);
  dim3 grid(16, 16, 16);
  msssim_l1_kernel<<<grid, dim3(256), 0, stream>>>(x, y, gm, out);
}

// Round 10
// 183.055 us; speedup vs baseline: 2.0394x; 1.0523x over previous
//
#include <hip/hip_runtime.h>

namespace {

constexpr float kAlpha = 0.025f;
constexpr float kC1 = 1.0e-4f;  // (0.01*1)^2
constexpr float kC2 = 9.0e-4f;  // (0.03*1)^2

constexpr int MPS = 68;  // mp row stride (shorts): 136 B, b64-aligned rows
constexpr int HTS = 68;  // hbT col stride (shorts): 136 B, b64-aligned

typedef __attribute__((ext_vector_type(8))) short short8;
typedef __attribute__((ext_vector_type(4))) float f32x4;

// LDS: union(mp 17.4 KB, hbT 52.2 KB) + red = 52.3 KB -> 3 blocks/CU
// (mp is dead after the A-fragment build barrier; hbT written only after)
// group1 planes: sigma s in {0,1,2}, map m -> plane s*4+m  (12 planes)
// group2 planes: sigma 3 map m -> plane m; sigma 4 map m -> plane 4+m; d -> 8
struct __align__(16) Smem {
  union {
    short mp[2][64 * MPS];    // bf16 pixel maps: x, y (staging only)
    short hbT[12][32 * HTS];  // bf16 H results, transposed [out_col][row]
  };
  float red[4];
};

union Frag {
  int i[4];
  short8 s8;
};

__device__ __forceinline__ unsigned f2bf(float f) {  // RNE fp32 -> bf16 bits
  unsigned u = __float_as_uint(f);
  return (u + 0x7FFFu + ((u >> 16) & 1u)) >> 16;
}
__device__ __forceinline__ unsigned pack2(float a, float b) {
  return f2bf(a) | (f2bf(b) << 16);
}
__device__ __forceinline__ float bfl(unsigned u) {
  return __uint_as_float(u << 16);
}
__device__ __forceinline__ float bfh(unsigned u) {
  return __uint_as_float(u & 0xFFFF0000u);
}

// W fragment via lane shuffles: element (p,h) = g[k - n],
// k = kt*32 + quad*8 + 2p+h, n = nt*16 + l16; lanes >= 33 hold 0 and the
// &63 wrap maps every out-of-band index onto a zero lane. Symmetric for
// A-operand (V pass) and B-operand (H pass) layouts.
__device__ __forceinline__ short8 wbuild(unsigned tb, int lane, int nt,
                                         int kt) {
  const int b0 = (lane >> 4) * 8 - (lane & 15) + 32 * kt - 16 * nt;
  Frag u;
#pragma unroll
  for (int p = 0; p < 4; ++p) {
    unsigned lo = (unsigned)__shfl((int)tb, (b0 + 2 * p) & 63, 64);
    unsigned hi = (unsigned)__shfl((int)tb, (b0 + 2 * p + 1) & 63, 64);
    u.i[p] = (int)(lo | (hi << 16));
  }
  return u.s8;
}

__device__ __forceinline__ void load_xy(const Smem& sm, int row, int quad,
                                        Frag fx[2], Frag fy[2]) {
  const short* px = &sm.mp[0][row * MPS + quad * 8];
  const short* py = &sm.mp[1][row * MPS + quad * 8];
  *(int2*)&fx[0].i[0] = *(const int2*)(px);
  *(int2*)&fx[0].i[2] = *(const int2*)(px + 4);
  *(int2*)&fx[1].i[0] = *(const int2*)(px + 32);
  *(int2*)&fx[1].i[2] = *(const int2*)(px + 36);
  *(int2*)&fy[0].i[0] = *(const int2*)(py);
  *(int2*)&fy[0].i[2] = *(const int2*)(py + 4);
  *(int2*)&fy[1].i[0] = *(const int2*)(py + 32);
  *(int2*)&fy[1].i[2] = *(const int2*)(py + 36);
}

__global__ __launch_bounds__(256, 2) void msssim_l1_kernel(
    const float* __restrict__ x, const float* __restrict__ y,
    const float* __restrict__ gm, float* __restrict__ out) {
  __shared__ Smem sm;
  const int tid = threadIdx.x;
  const int lane = tid & 63;
  const int w = tid >> 6;
  const int quad = lane >> 4;
  const int l16 = lane & 15;

  // per-lane taps (lane j<33 holds m[16][j]); per-sigma bf16 tap bits
  float traw[5];
#pragma unroll
  for (int s = 0; s < 5; ++s)
    traw[s] = (lane < 33) ? gm[s * 1089 + 16 * 33 + lane] : 0.f;
  unsigned tbs[5];
#pragma unroll
  for (int s = 0; s < 5; ++s)
    tbs[s] = f2bf(traw[s] * rsqrtf(__shfl(traw[s], 16, 64)));
  float corr;  // fp32/bf16 tap-sum compensation for the l1 conv (sigma 4)
  {
    float g = traw[4] * rsqrtf(__shfl(traw[4], 16, 64));
    float se = g, st = bfl(f2bf(g));
#pragma unroll
    for (int off = 32; off > 0; off >>= 1) {
      se += __shfl_xor(se, off, 64);
      st += __shfl_xor(st, off, 64);
    }
    float r1 = se / st;
    corr = r1 * r1;
  }

  // 64x64 halo patch, zero-padded; bf16 x/y maps in LDS (mp region)
  const float* xb = x + blockIdx.z * (512 * 512);
  const float* yb = y + blockIdx.z * (512 * 512);
  const int rb = blockIdx.y * 32 - 16;
  const int cb = blockIdx.x * 32 - 16;
  for (int f = tid; f < 1024; f += 256) {
    int pr = f >> 4;
    int pc = (f & 15) << 2;
    int gr = rb + pr, gc = cb + pc;
    float4 vx = make_float4(0.f, 0.f, 0.f, 0.f);
    float4 vy = vx;
    if (gr >= 0 && gr < 512 && gc >= 0 && gc < 512) {
      vx = *(const float4*)(xb + gr * 512 + gc);
      vy = *(const float4*)(yb + gr * 512 + gc);
    }
    const int base = pr * MPS + pc;
    *(int2*)(&sm.mp[0][base]) =
        make_int2((int)pack2(vx.x, vx.y), (int)pack2(vx.z, vx.w));
    *(int2*)(&sm.mp[1][base]) =
        make_int2((int)pack2(vy.x, vy.y), (int)pack2(vy.z, vy.w));
  }
  __syncthreads();  // B1: patch ready

  // persistent A-fragments for THIS wave's map (m = w), all 4 row tiles;
  // wave 0 additionally pre-builds |x-y| fragments (mp dies at B2)
  Frag A[4][2];
  Frag dA[4][2];
#pragma unroll
  for (int mt = 0; mt < 4; ++mt) {
    Frag fx[2], fy[2];
    load_xy(sm, mt * 16 + l16, quad, fx, fy);
    if (w == 0) {
      A[mt][0] = fx[0];
      A[mt][1] = fx[1];
#pragma unroll
      for (int h = 0; h < 2; ++h)
#pragma unroll
        for (int i = 0; i < 4; ++i) {
          unsigned ux = (unsigned)fx[h].i[i], uy = (unsigned)fy[h].i[i];
          dA[mt][h].i[i] = (int)pack2(fabsf(bfl(ux) - bfl(uy)),
                                      fabsf(bfh(ux) - bfh(uy)));
        }
    } else if (w == 1) {
      A[mt][0] = fy[0];
      A[mt][1] = fy[1];
    } else {
#pragma unroll
      for (int h = 0; h < 2; ++h)
#pragma unroll
        for (int i = 0; i < 4; ++i) {
          unsigned ux = (unsigned)fx[h].i[i], uy = (unsigned)fy[h].i[i];
          float xl = bfl(ux), xh = bfh(ux), yl = bfl(uy), yh = bfh(uy);
          A[mt][h].i[i] = (w == 2) ? (int)pack2(fmaf(xl, xl, yl * yl),
                                               fmaf(xh, xh, yh * yh))
                                   : (int)pack2(xl * yl, xh * yh);
        }
    }
  }
  __syncthreads();  // B2: all mp reads done -> hbT may overwrite the union

  const int mtv = w >> 1, ntv = w & 1;
  f32x4 Pcs = {1.f, 1.f, 1.f, 1.f};
  f32x4 lumP = {0.f, 0.f, 0.f, 0.f};
  f32x4 l1v = {0.f, 0.f, 0.f, 0.f};

  // ================= group 1: sigmas 0..2 =================
#pragma unroll
  for (int s = 0; s < 3; ++s) {  // H: wave w = map w, plane s*4+w
    short8 wf[2][2];
#pragma unroll
    for (int nt = 0; nt < 2; ++nt)
#pragma unroll
      for (int kt = 0; kt < 2; ++kt) wf[nt][kt] = wbuild(tbs[s], lane, nt, kt);
#pragma unroll
    for (int mt = 0; mt < 4; ++mt)
#pragma unroll
      for (int nt = 0; nt < 2; ++nt) {
        f32x4 acc = {0.f, 0.f, 0.f, 0.f};
        acc = __builtin_amdgcn_mfma_f32_16x16x32_bf16(A[mt][0].s8, wf[nt][0],
                                                      acc, 0, 0, 0);
        acc = __builtin_amdgcn_mfma_f32_16x16x32_bf16(A[mt][1].s8, wf[nt][1],
                                                      acc, 0, 0, 0);
        *(int2*)(&sm.hbT[s * 4 + w][(nt * 16 + l16) * HTS + mt * 16 +
                                    quad * 4]) =
            make_int2((int)pack2(acc[0], acc[1]), (int)pack2(acc[2], acc[3]));
      }
  }
  __syncthreads();  // B3: group-1 hbT ready

#pragma unroll
  for (int s = 0; s < 3; ++s) {  // V + combine: wave = output quadrant
    short8 wa0 = wbuild(tbs[s], lane, mtv, 0);
    short8 wa1 = wbuild(tbs[s], lane, mtv, 1);
    f32x4 va[4];
#pragma unroll
    for (int m = 0; m < 4; ++m) {
      const short* bp = &sm.hbT[s * 4 + m][(ntv * 16 + l16) * HTS + quad * 8];
      Frag b0, b1;
      *(int2*)&b0.i[0] = *(const int2*)(bp);
      *(int2*)&b0.i[2] = *(const int2*)(bp + 4);
      *(int2*)&b1.i[0] = *(const int2*)(bp + 32);
      *(int2*)&b1.i[2] = *(const int2*)(bp + 36);
      f32x4 acc = {0.f, 0.f, 0.f, 0.f};
      acc = __builtin_amdgcn_mfma_f32_16x16x32_bf16(wa0, b0.s8, acc, 0, 0, 0);
      acc = __builtin_amdgcn_mfma_f32_16x16x32_bf16(wa1, b1.s8, acc, 0, 0, 0);
      va[m] = acc;
    }
#pragma unroll
    for (int r = 0; r < 4; ++r) {
      float mux = va[0][r], muy = va[1][r], m2 = va[2][r], mxy = va[3][r];
      float cs = (2.f * (mxy - mux * muy) + kC2) /
                 ((m2 - mux * mux - muy * muy) + kC2);
      Pcs[r] *= cs;
    }
  }
  __syncthreads();  // B4: group-1 V reads done, hbT reusable

  // ================= group 2: sigmas 3,4 =================
#pragma unroll
  for (int s = 3; s < 5; ++s) {
    const int pb = (s == 3) ? 0 : 4;
    short8 wf[2][2];
#pragma unroll
    for (int nt = 0; nt < 2; ++nt)
#pragma unroll
      for (int kt = 0; kt < 2; ++kt) wf[nt][kt] = wbuild(tbs[s], lane, nt, kt);
#pragma unroll
    for (int mt = 0; mt < 4; ++mt)
#pragma unroll
      for (int nt = 0; nt < 2; ++nt) {
        f32x4 acc = {0.f, 0.f, 0.f, 0.f};
        acc = __builtin_amdgcn_mfma_f32_16x16x32_bf16(A[mt][0].s8, wf[nt][0],
                                                      acc, 0, 0, 0);
        acc = __builtin_amdgcn_mfma_f32_16x16x32_bf16(A[mt][1].s8, wf[nt][1],
                                                      acc, 0, 0, 0);
        *(int2*)(&sm.hbT[pb + w][(nt * 16 + l16) * HTS + mt * 16 + quad * 4]) =
            make_int2((int)pack2(acc[0], acc[1]), (int)pack2(acc[2], acc[3]));
      }
  }
  if (w == 0) {  // extra plane: sigma-4 |x-y| -> plane 8 (registers, mp dead)
    short8 wf[2][2];
#pragma unroll
    for (int nt = 0; nt < 2; ++nt)
#pragma unroll
      for (int kt = 0; kt < 2; ++kt) wf[nt][kt] = wbuild(tbs[4], lane, nt, kt);
#pragma unroll
    for (int mt = 0; mt < 4; ++mt) {
#pragma unroll
      for (int nt = 0; nt < 2; ++nt) {
        f32x4 acc = {0.f, 0.f, 0.f, 0.f};
        acc = __builtin_amdgcn_mfma_f32_16x16x32_bf16(dA[mt][0].s8, wf[nt][0],
                                                      acc, 0, 0, 0);
        acc = __builtin_amdgcn_mfma_f32_16x16x32_bf16(dA[mt][1].s8, wf[nt][1],
                                                      acc, 0, 0, 0);
        *(int2*)(&sm.hbT[8][(nt * 16 + l16) * HTS + mt * 16 + quad * 4]) =
            make_int2((int)pack2(acc[0], acc[1]), (int)pack2(acc[2], acc[3]));
      }
    }
  }
  __syncthreads();  // B5: group-2 hbT ready

#pragma unroll
  for (int s = 3; s < 5; ++s) {
    const int pb = (s == 3) ? 0 : 4;
    const int nm = (s == 3) ? 4 : 5;
    short8 wa0 = wbuild(tbs[s], lane, mtv, 0);
    short8 wa1 = wbuild(tbs[s], lane, mtv, 1);
    f32x4 va[5];
#pragma unroll
    for (int m = 0; m < 5; ++m) {
      if (m >= nm) continue;
      const short* bp = &sm.hbT[pb + m][(ntv * 16 + l16) * HTS + quad * 8];
      Frag b0, b1;
      *(int2*)&b0.i[0] = *(const int2*)(bp);
      *(int2*)&b0.i[2] = *(const int2*)(bp + 4);
      *(int2*)&b1.i[0] = *(const int2*)(bp + 32);
      *(int2*)&b1.i[2] = *(const int2*)(bp + 36);
      f32x4 acc = {0.f, 0.f, 0.f, 0.f};
      acc = __builtin_amdgcn_mfma_f32_16x16x32_bf16(wa0, b0.s8, acc, 0, 0, 0);
      acc = __builtin_amdgcn_mfma_f32_16x16x32_bf16(wa1, b1.s8, acc, 0, 0, 0);
      va[m] = acc;
    }
#pragma unroll
    for (int r = 0; r < 4; ++r) {
      float mux = va[0][r], muy = va[1][r], m2 = va[2][r], mxy = va[3][r];
      float mux2 = mux * mux, muy2 = muy * muy, muxy = mux * muy;
      float cs = (2.f * (mxy - muxy) + kC2) / ((m2 - mux2 - muy2) + kC2);
      Pcs[r] *= cs;
      if (s == 4) {
        lumP[r] = ((2.f * muxy + kC1) / (mux2 + muy2 + kC1)) * Pcs[r];
        l1v[r] = va[4][r] * corr;
      }
    }
  }

  // loss_mix = alpha*(1 - lum*PIcs) + (1-alpha)*gaussian_l1 ; out = 20*mean
  float lsum = 0.f;
#pragma unroll
  for (int r = 0; r < 4; ++r)
    lsum += kAlpha * (1.f - lumP[r]) + (1.f - kAlpha) * l1v[r];
#pragma unroll
  for (int off = 32; off > 0; off >>= 1) lsum += __shfl_down(lsum, off, 64);
  if ((tid & 63) == 0) sm.red[tid >> 6] = lsum;
  __syncthreads();  // B6
  if (tid == 0) {
    float t = sm.red[0] + sm.red[1] + sm.red[2] + sm.red[3];
    atomicAdd(out, t * (20.f / (16.f * 512.f * 512.f)));
  }
}

}  // namespace

extern "C" void kernel_launch(void* const* d_in, const int* in_sizes, int n_in,
                              void* d_out, int out_size, void* d_ws,
                              size_t ws_size, hipStream_t stream) {
  (void)in_sizes;
  (void)n_in;
  (void)d_ws;
  (void)ws_size;
  (void)out_size;
  const float* x = (const float*)d_in[0];
  const float* y = (const float*)d_in[1];
  const float* gm = (const float*)d_in[2];
  float* out = (float*)d_out;
  hipMemsetAsync(out, 0, sizeof(float), stream);
  dim3 grid(16, 16, 16);
  msssim_l1_kernel<<<grid, dim3(256), 0, stream>>>(x, y, gm, out);
}